// Round 7
// baseline (188.082 us; speedup 1.0000x reference)
//
#include <hip/hip_runtime.h>

// AGNNConv on gfx950 — MEASUREMENT ROUND: kernels identical to R6; agg is
// launched 3x (idempotent) so T7 - T6 = 2*t_agg resolves the per-kernel
// split that the fill-crowded rocprof top-5 cannot show.
//   Xp = bf16(X @ W)   (MFMA 16x16x32 bf16; one 16-row tile per WAVE, rowptr fused)
//   out[r] = sum_e exp(aw*<Xp[r],Xp[c]>)*Xp[c] / sum_e exp(...)
// N=100000, E=1200000, D=64.

typedef __attribute__((ext_vector_type(8))) short short8;
typedef __attribute__((ext_vector_type(4))) float f32x4;

__device__ __forceinline__ unsigned short f2bf(float f) {   // RNE f32->bf16
    unsigned u = __float_as_uint(f);
    return (unsigned short)((u + 0x7fffu + ((u >> 16) & 1u)) >> 16);
}
__device__ __forceinline__ float blo(unsigned u) { return __uint_as_float(u << 16); }
__device__ __forceinline__ float bhi(unsigned u) { return __uint_as_float(u & 0xffff0000u); }

// ---- K1: fused CSR rowptr build + Xp = bf16(X @ W) via MFMA ---------------
__global__ __launch_bounds__(256) void gemm_rowptr(
    const float* __restrict__ X, const float* __restrict__ W,
    const int* __restrict__ row, unsigned short* __restrict__ Xpb,
    int* __restrict__ rp, int N, int E)
{
    {
        const int stride = gridDim.x * 256;
        for (int e = blockIdx.x * 256 + threadIdx.x; e < E; e += stride) {
            int r = row[e];
            if (e == 0)                rp[r] = 0;
            else if (row[e - 1] != r)  rp[r] = e;
            if (e == E - 1)            rp[N] = E;
        }
    }

    const int lane = threadIdx.x & 63;
    const int m    = lane & 15;              // A-row / B-col / D-col
    const int kb   = (lane >> 4) << 3;       // k-base: 0,8,16,24

    short8 b0[4], b1[4];
#pragma unroll
    for (int cb = 0; cb < 4; ++cb) {
        const float* wc = W + (size_t)kb * 64 + 16 * cb + m;
#pragma unroll
        for (int j = 0; j < 8; ++j) b0[cb][j] = f2bf(wc[j * 64]);
#pragma unroll
        for (int j = 0; j < 8; ++j) b1[cb][j] = f2bf(wc[(j + 32) * 64]);
    }

    const int ntiles = (N + 15) >> 4;
    const int gwaves = gridDim.x << 2;
    for (int t = (blockIdx.x << 2) + (threadIdx.x >> 6); t < ntiles; t += gwaves) {
        const int r0 = t << 4;
        const int rA = min(r0 + m, N - 1);
        const float* xr = X + (size_t)rA * 64 + kb;
        float4 aL0 = *(const float4*)(xr);
        float4 aH0 = *(const float4*)(xr + 4);
        float4 aL1 = *(const float4*)(xr + 32);
        float4 aH1 = *(const float4*)(xr + 36);
        short8 a0, a1;
        a0[0]=f2bf(aL0.x); a0[1]=f2bf(aL0.y); a0[2]=f2bf(aL0.z); a0[3]=f2bf(aL0.w);
        a0[4]=f2bf(aH0.x); a0[5]=f2bf(aH0.y); a0[6]=f2bf(aH0.z); a0[7]=f2bf(aH0.w);
        a1[0]=f2bf(aL1.x); a1[1]=f2bf(aL1.y); a1[2]=f2bf(aL1.z); a1[3]=f2bf(aL1.w);
        a1[4]=f2bf(aH1.x); a1[5]=f2bf(aH1.y); a1[6]=f2bf(aH1.z); a1[7]=f2bf(aH1.w);

        f32x4 acc0 = {0.f,0.f,0.f,0.f}, acc1 = acc0, acc2 = acc0, acc3 = acc0;
        acc0 = __builtin_amdgcn_mfma_f32_16x16x32_bf16(a0, b0[0], acc0, 0, 0, 0);
        acc1 = __builtin_amdgcn_mfma_f32_16x16x32_bf16(a0, b0[1], acc1, 0, 0, 0);
        acc2 = __builtin_amdgcn_mfma_f32_16x16x32_bf16(a0, b0[2], acc2, 0, 0, 0);
        acc3 = __builtin_amdgcn_mfma_f32_16x16x32_bf16(a0, b0[3], acc3, 0, 0, 0);
        acc0 = __builtin_amdgcn_mfma_f32_16x16x32_bf16(a1, b1[0], acc0, 0, 0, 0);
        acc1 = __builtin_amdgcn_mfma_f32_16x16x32_bf16(a1, b1[1], acc1, 0, 0, 0);
        acc2 = __builtin_amdgcn_mfma_f32_16x16x32_bf16(a1, b1[2], acc2, 0, 0, 0);
        acc3 = __builtin_amdgcn_mfma_f32_16x16x32_bf16(a1, b1[3], acc3, 0, 0, 0);

        const int rD = r0 + ((lane >> 4) << 2);
        unsigned short* o = Xpb + (size_t)rD * 64 + m;
#pragma unroll
        for (int j = 0; j < 4; ++j) {
            if (rD + j < N) {
                o[j * 64 +  0] = f2bf(acc0[j]);
                o[j * 64 + 16] = f2bf(acc1[j]);
                o[j * 64 + 32] = f2bf(acc2[j]);
                o[j * 64 + 48] = f2bf(acc3[j]);
            }
        }
    }
}

// ---- K2: aggregation (identical to R6) ------------------------------------
#define DPP_ADD(P, CTRL)                                                          \
    P += __int_as_float(__builtin_amdgcn_update_dpp(                              \
        __float_as_int(P), __float_as_int(P), CTRL, 0xf, 0xf, false));

#define AGG_STEP(G, OFF)                                                          \
    {                                                                             \
        float x0 = blo(G.x), x1 = bhi(G.x), x2 = blo(G.y), x3 = bhi(G.y);         \
        float p = x0 * xr0;                                                       \
        p = fmaf(x1, xr1, p);                                                     \
        p = fmaf(x2, xr2, p);                                                     \
        p = fmaf(x3, xr3, p);                                                     \
        DPP_ADD(p, 0xB1)   /* quad_perm xor1 */                                   \
        DPP_ADD(p, 0x4E)   /* quad_perm xor2 */                                   \
        DPP_ADD(p, 0x141)  /* row_half_mirror = xor4 */                           \
        DPP_ADD(p, 0x140)  /* row_mirror      = xor8 */                           \
        float att = exp2f(p * aw2);                                               \
        att = (e + OFF < end) ? att : 0.f;                                        \
        acc0 = fmaf(att, x0, acc0);                                               \
        acc1 = fmaf(att, x1, acc1);                                               \
        acc2 = fmaf(att, x2, acc2);                                               \
        acc3 = fmaf(att, x3, acc3);                                               \
        rs += att;                                                                \
    }

#define CL(i)  col[min((i), cap)]
#define GX(c)  (*(const uint2*)(xb + ((size_t)(c) << 7)))

__global__ __launch_bounds__(256) void agg(
    const unsigned short* __restrict__ Xpb, const int* __restrict__ rp,
    const int* __restrict__ col, const float* __restrict__ attw,
    float* __restrict__ out, int N)
{
    const int lane = threadIdx.x & 63;
    const int t    = lane & 15;
    const int wid  = (int)((blockIdx.x * blockDim.x + threadIdx.x) >> 6);
    const int r    = (wid << 2) + (lane >> 4);
    if ((wid << 2) >= N) return;
    const int  rr    = (r < N) ? r : (N - 1);
    const bool rowok = (r < N);

    const float aw2   = attw[0] * 1.4426950408889634f;
    const int   start = rp[rr];
    const int   end   = rowok ? rp[rr + 1] : start;
    const int   cap   = (end > start) ? (end - 1) : start;

    const char* xb = (const char*)Xpb + (t << 3);
    uint2 xw = *(const uint2*)(xb + ((size_t)rr << 7));
    const float xr0 = blo(xw.x), xr1 = bhi(xw.x), xr2 = blo(xw.y), xr3 = bhi(xw.y);

    float acc0 = 0.f, acc1 = 0.f, acc2 = 0.f, acc3 = 0.f, rs = 0.f;

    uint2 g0 = GX(CL(start + 0)), g1 = GX(CL(start + 1)),
          g2 = GX(CL(start + 2)), g3 = GX(CL(start + 3));
    uint2 h0 = GX(CL(start + 4)), h1 = GX(CL(start + 5)),
          h2 = GX(CL(start + 6)), h3 = GX(CL(start + 7));
    uint2 i0 = GX(CL(start + 8)), i1 = GX(CL(start + 9)),
          i2 = GX(CL(start +10)), i3 = GX(CL(start +11));
    int n0 = CL(start + 12), n1 = CL(start + 13),
        n2 = CL(start + 14), n3 = CL(start + 15);

    for (int e = start; e < end; e += 4) {
        uint2 j0 = GX(n0), j1 = GX(n1), j2 = GX(n2), j3 = GX(n3);
        n0 = CL(e + 16); n1 = CL(e + 17); n2 = CL(e + 18); n3 = CL(e + 19);

        AGG_STEP(g0, 0)
        AGG_STEP(g1, 1)
        AGG_STEP(g2, 2)
        AGG_STEP(g3, 3)

        g0 = h0; g1 = h1; g2 = h2; g3 = h3;
        h0 = i0; h1 = i1; h2 = i2; h3 = i3;
        i0 = j0; i1 = j1; i2 = j2; i3 = j3;
    }

    if (rowok) {
        float inv = 1.0f / rs;
        *(float4*)(out + ((size_t)r << 6) + (t << 2)) =
            make_float4(acc0 * inv, acc1 * inv, acc2 * inv, acc3 * inv);
    }
}

// ---------------------------------------------------------------------------
extern "C" void kernel_launch(void* const* d_in, const int* in_sizes, int n_in,
                              void* d_out, int out_size, void* d_ws, size_t ws_size,
                              hipStream_t stream)
{
    const float* X    = (const float*)d_in[0];
    const float* W    = (const float*)d_in[1];
    const float* attw = (const float*)d_in[2];
    const int*   row  = (const int*)d_in[3];
    const int*   col  = (const int*)d_in[4];
    float*       out  = (float*)d_out;

    const int N = in_sizes[0] / 64;
    const int E = in_sizes[3];

    unsigned short* Xpb = (unsigned short*)d_ws;
    int* rp = (int*)((char*)d_ws + (size_t)N * 64 * sizeof(unsigned short));

    const int ntiles = (N + 15) >> 4;
    gemm_rowptr<<<(ntiles + 3) / 4, 256, 0, stream>>>(X, W, row, Xpb, rp, N, E);

    int waves = (N + 3) / 4;
    int gb2   = (waves * 64 + 255) / 256;
    // agg launched 3x — idempotent; T(this) - T(prev) = 2 * t_agg.
    agg<<<gb2, 256, 0, stream>>>(Xpb, rp, col, attw, out, N);
    agg<<<gb2, 256, 0, stream>>>(Xpb, rp, col, attw, out, N);
    agg<<<gb2, 256, 0, stream>>>(Xpb, rp, col, attw, out, N);
}

// Round 8
// 120.734 us; speedup vs baseline: 1.5578x; 1.5578x over previous
//
#include <hip/hip_runtime.h>

// AGNNConv on gfx950:
//   Xp = bf16(X @ W)   (MFMA 16x16x32 bf16; one 16-row tile per WAVE, rowptr fused)
//   out[r] = sum_e exp(aw*<Xp[r],Xp[c]>)*Xp[c] / sum_e exp(...)
// N=100000, E=1200000, D=64.
// agg: 4 rows/wave, 16 lanes/row, 4 bf16 feats/lane; depth-3 gather pipeline
// with STATIC slots (A/B/C, hand-unrolled 3x) — no rotation movs, so the
// compiler emits counted vmcnt waits instead of draining the newest gathers
// every iteration (the R4-R6 latency bug).

typedef __attribute__((ext_vector_type(8))) short short8;
typedef __attribute__((ext_vector_type(4))) float f32x4;

__device__ __forceinline__ unsigned short f2bf(float f) {   // RNE f32->bf16
    unsigned u = __float_as_uint(f);
    return (unsigned short)((u + 0x7fffu + ((u >> 16) & 1u)) >> 16);
}
__device__ __forceinline__ float blo(unsigned u) { return __uint_as_float(u << 16); }
__device__ __forceinline__ float bhi(unsigned u) { return __uint_as_float(u & 0xffff0000u); }

// ---- K1: fused CSR rowptr build + Xp = bf16(X @ W) via MFMA ---------------
__global__ __launch_bounds__(256) void gemm_rowptr(
    const float* __restrict__ X, const float* __restrict__ W,
    const int* __restrict__ row, unsigned short* __restrict__ Xpb,
    int* __restrict__ rp, int N, int E)
{
    {
        const int stride = gridDim.x * 256;
        for (int e = blockIdx.x * 256 + threadIdx.x; e < E; e += stride) {
            int r = row[e];
            if (e == 0)                rp[r] = 0;
            else if (row[e - 1] != r)  rp[r] = e;
            if (e == E - 1)            rp[N] = E;
        }
    }

    const int lane = threadIdx.x & 63;
    const int m    = lane & 15;              // A-row / B-col / D-col
    const int kb   = (lane >> 4) << 3;       // k-base: 0,8,16,24

    short8 b0[4], b1[4];
#pragma unroll
    for (int cb = 0; cb < 4; ++cb) {
        const float* wc = W + (size_t)kb * 64 + 16 * cb + m;
#pragma unroll
        for (int j = 0; j < 8; ++j) b0[cb][j] = f2bf(wc[j * 64]);
#pragma unroll
        for (int j = 0; j < 8; ++j) b1[cb][j] = f2bf(wc[(j + 32) * 64]);
    }

    const int ntiles = (N + 15) >> 4;
    const int gwaves = gridDim.x << 2;
    for (int t = (blockIdx.x << 2) + (threadIdx.x >> 6); t < ntiles; t += gwaves) {
        const int r0 = t << 4;
        const int rA = min(r0 + m, N - 1);
        const float* xr = X + (size_t)rA * 64 + kb;
        float4 aL0 = *(const float4*)(xr);
        float4 aH0 = *(const float4*)(xr + 4);
        float4 aL1 = *(const float4*)(xr + 32);
        float4 aH1 = *(const float4*)(xr + 36);
        short8 a0, a1;
        a0[0]=f2bf(aL0.x); a0[1]=f2bf(aL0.y); a0[2]=f2bf(aL0.z); a0[3]=f2bf(aL0.w);
        a0[4]=f2bf(aH0.x); a0[5]=f2bf(aH0.y); a0[6]=f2bf(aH0.z); a0[7]=f2bf(aH0.w);
        a1[0]=f2bf(aL1.x); a1[1]=f2bf(aL1.y); a1[2]=f2bf(aL1.z); a1[3]=f2bf(aL1.w);
        a1[4]=f2bf(aH1.x); a1[5]=f2bf(aH1.y); a1[6]=f2bf(aH1.z); a1[7]=f2bf(aH1.w);

        f32x4 acc0 = {0.f,0.f,0.f,0.f}, acc1 = acc0, acc2 = acc0, acc3 = acc0;
        acc0 = __builtin_amdgcn_mfma_f32_16x16x32_bf16(a0, b0[0], acc0, 0, 0, 0);
        acc1 = __builtin_amdgcn_mfma_f32_16x16x32_bf16(a0, b0[1], acc1, 0, 0, 0);
        acc2 = __builtin_amdgcn_mfma_f32_16x16x32_bf16(a0, b0[2], acc2, 0, 0, 0);
        acc3 = __builtin_amdgcn_mfma_f32_16x16x32_bf16(a0, b0[3], acc3, 0, 0, 0);
        acc0 = __builtin_amdgcn_mfma_f32_16x16x32_bf16(a1, b1[0], acc0, 0, 0, 0);
        acc1 = __builtin_amdgcn_mfma_f32_16x16x32_bf16(a1, b1[1], acc1, 0, 0, 0);
        acc2 = __builtin_amdgcn_mfma_f32_16x16x32_bf16(a1, b1[2], acc2, 0, 0, 0);
        acc3 = __builtin_amdgcn_mfma_f32_16x16x32_bf16(a1, b1[3], acc3, 0, 0, 0);

        const int rD = r0 + ((lane >> 4) << 2);
        unsigned short* o = Xpb + (size_t)rD * 64 + m;
#pragma unroll
        for (int j = 0; j < 4; ++j) {
            if (rD + j < N) {
                o[j * 64 +  0] = f2bf(acc0[j]);
                o[j * 64 + 16] = f2bf(acc1[j]);
                o[j * 64 + 32] = f2bf(acc2[j]);
                o[j * 64 + 48] = f2bf(acc3[j]);
            }
        }
    }
}

// ---- K2: aggregation -------------------------------------------------------
#define DPP_ADD(P, CTRL)                                                          \
    P += __int_as_float(__builtin_amdgcn_update_dpp(                              \
        __float_as_int(P), __float_as_int(P), CTRL, 0xf, 0xf, false));

#define AGG_STEP(G, OFF)                                                          \
    {                                                                             \
        float x0 = blo(G.x), x1 = bhi(G.x), x2 = blo(G.y), x3 = bhi(G.y);         \
        float p = x0 * xr0;                                                       \
        p = fmaf(x1, xr1, p);                                                     \
        p = fmaf(x2, xr2, p);                                                     \
        p = fmaf(x3, xr3, p);                                                     \
        DPP_ADD(p, 0xB1)   /* quad_perm xor1 */                                   \
        DPP_ADD(p, 0x4E)   /* quad_perm xor2 */                                   \
        DPP_ADD(p, 0x141)  /* row_half_mirror = xor4 */                           \
        DPP_ADD(p, 0x140)  /* row_mirror      = xor8 */                           \
        float att = __builtin_amdgcn_exp2f(p * aw2);                              \
        att = (e + OFF < end) ? att : 0.f;                                        \
        acc0 = fmaf(att, x0, acc0);                                               \
        acc1 = fmaf(att, x1, acc1);                                               \
        acc2 = fmaf(att, x2, acc2);                                               \
        acc3 = fmaf(att, x3, acc3);                                               \
        rs += att;                                                                \
    }

#define CL(i)  col[min((i), cap)]
#define GX(c)  (*(const uint2*)(xb + ((size_t)(c) << 7)))

// one pipeline sub-iteration on static slot S (S0..S3, nS0..nS3):
// consume packet e -> regather S for packet e+12 -> load S-cols for e+24.
#define SUBITER(S0,S1,S2,S3, nS0,nS1,nS2,nS3)                                     \
    AGG_STEP(S0, 0) AGG_STEP(S1, 1) AGG_STEP(S2, 2) AGG_STEP(S3, 3)               \
    if (e + 4 >= end) break;                                                      \
    S0 = GX(nS0); S1 = GX(nS1); S2 = GX(nS2); S3 = GX(nS3);                       \
    nS0 = CL(e + 24); nS1 = CL(e + 25); nS2 = CL(e + 26); nS3 = CL(e + 27);       \
    e += 4;

__global__ __launch_bounds__(256) void agg(
    const unsigned short* __restrict__ Xpb, const int* __restrict__ rp,
    const int* __restrict__ col, const float* __restrict__ attw,
    float* __restrict__ out, int N)
{
    const int lane = threadIdx.x & 63;
    const int t    = lane & 15;
    const int wid  = (int)((blockIdx.x * blockDim.x + threadIdx.x) >> 6);
    const int r    = (wid << 2) + (lane >> 4);
    if ((wid << 2) >= N) return;
    const int  rr    = (r < N) ? r : (N - 1);
    const bool rowok = (r < N);

    const float aw2   = attw[0] * 1.4426950408889634f;   // fold ln2: exp->exp2
    const int   start = rp[rr];
    const int   end   = rowok ? rp[rr + 1] : start;
    const int   cap   = (end > start) ? (end - 1) : start;

    const char* xb = (const char*)Xpb + (t << 3);
    uint2 xw = *(const uint2*)(xb + ((size_t)rr << 7));
    const float xr0 = blo(xw.x), xr1 = bhi(xw.x), xr2 = blo(xw.y), xr3 = bhi(xw.y);

    float acc0 = 0.f, acc1 = 0.f, acc2 = 0.f, acc3 = 0.f, rs = 0.f;

    // prologue: slots A,B,C = packets 0,1,2; nA,nB,nC = cols for packets 3,4,5
    uint2 A0 = GX(CL(start + 0)), A1 = GX(CL(start + 1)),
          A2 = GX(CL(start + 2)), A3 = GX(CL(start + 3));
    uint2 B0 = GX(CL(start + 4)), B1 = GX(CL(start + 5)),
          B2 = GX(CL(start + 6)), B3 = GX(CL(start + 7));
    uint2 C0 = GX(CL(start + 8)), C1 = GX(CL(start + 9)),
          C2 = GX(CL(start +10)), C3 = GX(CL(start +11));
    int nA0 = CL(start + 12), nA1 = CL(start + 13),
        nA2 = CL(start + 14), nA3 = CL(start + 15);
    int nB0 = CL(start + 16), nB1 = CL(start + 17),
        nB2 = CL(start + 18), nB3 = CL(start + 19);
    int nC0 = CL(start + 20), nC1 = CL(start + 21),
        nC2 = CL(start + 22), nC3 = CL(start + 23);

    int e = start;
    for (;;) {
        SUBITER(A0,A1,A2,A3, nA0,nA1,nA2,nA3)
        SUBITER(B0,B1,B2,B3, nB0,nB1,nB2,nB3)
        SUBITER(C0,C1,C2,C3, nC0,nC1,nC2,nC3)
    }

    if (rowok) {
        float inv = 1.0f / rs;
        *(float4*)(out + ((size_t)r << 6) + (t << 2)) =
            make_float4(acc0 * inv, acc1 * inv, acc2 * inv, acc3 * inv);
    }
}

// ---------------------------------------------------------------------------
extern "C" void kernel_launch(void* const* d_in, const int* in_sizes, int n_in,
                              void* d_out, int out_size, void* d_ws, size_t ws_size,
                              hipStream_t stream)
{
    const float* X    = (const float*)d_in[0];
    const float* W    = (const float*)d_in[1];
    const float* attw = (const float*)d_in[2];
    const int*   row  = (const int*)d_in[3];
    const int*   col  = (const int*)d_in[4];
    float*       out  = (float*)d_out;

    const int N = in_sizes[0] / 64;
    const int E = in_sizes[3];

    unsigned short* Xpb = (unsigned short*)d_ws;
    int* rp = (int*)((char*)d_ws + (size_t)N * 64 * sizeof(unsigned short));

    const int ntiles = (N + 15) >> 4;
    gemm_rowptr<<<(ntiles + 3) / 4, 256, 0, stream>>>(X, W, row, Xpb, rp, N, E);

    int waves = (N + 3) / 4;
    int gb2   = (waves * 64 + 255) / 256;
    agg<<<gb2, 256, 0, stream>>>(Xpb, rp, col, attw, out, N);
}

// Round 10
// 119.450 us; speedup vs baseline: 1.5746x; 1.0108x over previous
//
#include <hip/hip_runtime.h>

// AGNNConv on gfx950:
//   Xp = bf16(X @ W)   (MFMA 16x16x32 bf16; one 16-row tile per WAVE, rowptr fused)
//   out[r] = sum_e exp(aw*<Xp[r],Xp[c]>)*Xp[c] / sum_e exp(...)
// N=100000, E=1200000, D=64.
// agg: 4 rows/wave, 16 lanes/row, 4 bf16 feats/lane; depth-2 STATIC slots with
// CONDITIONAL regather — issues ~1.05x the useful gathers (depth-3 uncond
// issued ~1.67x: clamped prologue+tail refills are real memory requests).
// [R9 was an infra timeout; this is the unmeasured R8 kernel resubmitted.]

typedef __attribute__((ext_vector_type(8))) short short8;
typedef __attribute__((ext_vector_type(4))) float f32x4;

__device__ __forceinline__ unsigned short f2bf(float f) {   // RNE f32->bf16
    unsigned u = __float_as_uint(f);
    return (unsigned short)((u + 0x7fffu + ((u >> 16) & 1u)) >> 16);
}
__device__ __forceinline__ float blo(unsigned u) { return __uint_as_float(u << 16); }
__device__ __forceinline__ float bhi(unsigned u) { return __uint_as_float(u & 0xffff0000u); }

// ---- K1: fused CSR rowptr build + Xp = bf16(X @ W) via MFMA ---------------
__global__ __launch_bounds__(256) void gemm_rowptr(
    const float* __restrict__ X, const float* __restrict__ W,
    const int* __restrict__ row, unsigned short* __restrict__ Xpb,
    int* __restrict__ rp, int N, int E)
{
    {
        const int stride = gridDim.x * 256;
        for (int e = blockIdx.x * 256 + threadIdx.x; e < E; e += stride) {
            int r = row[e];
            if (e == 0)                rp[r] = 0;
            else if (row[e - 1] != r)  rp[r] = e;
            if (e == E - 1)            rp[N] = E;
        }
    }

    const int lane = threadIdx.x & 63;
    const int m    = lane & 15;              // A-row / B-col / D-col
    const int kb   = (lane >> 4) << 3;       // k-base: 0,8,16,24

    short8 b0[4], b1[4];
#pragma unroll
    for (int cb = 0; cb < 4; ++cb) {
        const float* wc = W + (size_t)kb * 64 + 16 * cb + m;
#pragma unroll
        for (int j = 0; j < 8; ++j) b0[cb][j] = f2bf(wc[j * 64]);
#pragma unroll
        for (int j = 0; j < 8; ++j) b1[cb][j] = f2bf(wc[(j + 32) * 64]);
    }

    const int ntiles = (N + 15) >> 4;
    const int gwaves = gridDim.x << 2;
    for (int t = (blockIdx.x << 2) + (threadIdx.x >> 6); t < ntiles; t += gwaves) {
        const int r0 = t << 4;
        const int rA = min(r0 + m, N - 1);
        const float* xr = X + (size_t)rA * 64 + kb;
        float4 aL0 = *(const float4*)(xr);
        float4 aH0 = *(const float4*)(xr + 4);
        float4 aL1 = *(const float4*)(xr + 32);
        float4 aH1 = *(const float4*)(xr + 36);
        short8 a0, a1;
        a0[0]=f2bf(aL0.x); a0[1]=f2bf(aL0.y); a0[2]=f2bf(aL0.z); a0[3]=f2bf(aL0.w);
        a0[4]=f2bf(aH0.x); a0[5]=f2bf(aH0.y); a0[6]=f2bf(aH0.z); a0[7]=f2bf(aH0.w);
        a1[0]=f2bf(aL1.x); a1[1]=f2bf(aL1.y); a1[2]=f2bf(aL1.z); a1[3]=f2bf(aL1.w);
        a1[4]=f2bf(aH1.x); a1[5]=f2bf(aH1.y); a1[6]=f2bf(aH1.z); a1[7]=f2bf(aH1.w);

        f32x4 acc0 = {0.f,0.f,0.f,0.f}, acc1 = acc0, acc2 = acc0, acc3 = acc0;
        acc0 = __builtin_amdgcn_mfma_f32_16x16x32_bf16(a0, b0[0], acc0, 0, 0, 0);
        acc1 = __builtin_amdgcn_mfma_f32_16x16x32_bf16(a0, b0[1], acc1, 0, 0, 0);
        acc2 = __builtin_amdgcn_mfma_f32_16x16x32_bf16(a0, b0[2], acc2, 0, 0, 0);
        acc3 = __builtin_amdgcn_mfma_f32_16x16x32_bf16(a0, b0[3], acc3, 0, 0, 0);
        acc0 = __builtin_amdgcn_mfma_f32_16x16x32_bf16(a1, b1[0], acc0, 0, 0, 0);
        acc1 = __builtin_amdgcn_mfma_f32_16x16x32_bf16(a1, b1[1], acc1, 0, 0, 0);
        acc2 = __builtin_amdgcn_mfma_f32_16x16x32_bf16(a1, b1[2], acc2, 0, 0, 0);
        acc3 = __builtin_amdgcn_mfma_f32_16x16x32_bf16(a1, b1[3], acc3, 0, 0, 0);

        const int rD = r0 + ((lane >> 4) << 2);
        unsigned short* o = Xpb + (size_t)rD * 64 + m;
#pragma unroll
        for (int j = 0; j < 4; ++j) {
            if (rD + j < N) {
                o[j * 64 +  0] = f2bf(acc0[j]);
                o[j * 64 + 16] = f2bf(acc1[j]);
                o[j * 64 + 32] = f2bf(acc2[j]);
                o[j * 64 + 48] = f2bf(acc3[j]);
            }
        }
    }
}

// ---- K2: aggregation -------------------------------------------------------
#define DPP_ADD(P, CTRL)                                                          \
    P += __int_as_float(__builtin_amdgcn_update_dpp(                              \
        __float_as_int(P), __float_as_int(P), CTRL, 0xf, 0xf, false));

#define AGG_STEP(G, OFF)                                                          \
    {                                                                             \
        float x0 = blo(G.x), x1 = bhi(G.x), x2 = blo(G.y), x3 = bhi(G.y);         \
        float p = x0 * xr0;                                                       \
        p = fmaf(x1, xr1, p);                                                     \
        p = fmaf(x2, xr2, p);                                                     \
        p = fmaf(x3, xr3, p);                                                     \
        DPP_ADD(p, 0xB1)   /* quad_perm xor1 */                                   \
        DPP_ADD(p, 0x4E)   /* quad_perm xor2 */                                   \
        DPP_ADD(p, 0x141)  /* row_half_mirror = xor4 */                           \
        DPP_ADD(p, 0x140)  /* row_mirror      = xor8 */                           \
        float att = __builtin_amdgcn_exp2f(p * aw2);                              \
        att = (e + OFF < end) ? att : 0.f;                                        \
        acc0 = fmaf(att, x0, acc0);                                               \
        acc1 = fmaf(att, x1, acc1);                                               \
        acc2 = fmaf(att, x2, acc2);                                               \
        acc3 = fmaf(att, x3, acc3);                                               \
        rs += att;                                                                \
    }

#define CL(i)  col[min((i), cap)]
#define GX(c)  (*(const uint2*)(xb + ((size_t)(c) << 7)))

// consume static slot S (packet e), conditionally regather S for packet e+8.
// The regather condition (e+8 < end) is uniform within each 16-lane group ->
// clean exec-mask; skipped refills leave stale (finite) data consumed with
// att masked to 0.
#define SUBITER2(S0,S1,S2,S3, nS0,nS1,nS2,nS3)                                    \
    AGG_STEP(S0, 0) AGG_STEP(S1, 1) AGG_STEP(S2, 2) AGG_STEP(S3, 3)               \
    if (e + 8 < end) {                                                            \
        S0 = GX(nS0); S1 = GX(nS1); S2 = GX(nS2); S3 = GX(nS3);                   \
        nS0 = CL(e + 16); nS1 = CL(e + 17); nS2 = CL(e + 18); nS3 = CL(e + 19);   \
    }                                                                             \
    e += 4;                                                                       \
    if (e >= end) break;

__global__ __launch_bounds__(256) void agg(
    const unsigned short* __restrict__ Xpb, const int* __restrict__ rp,
    const int* __restrict__ col, const float* __restrict__ attw,
    float* __restrict__ out, int N)
{
    const int lane = threadIdx.x & 63;
    const int t    = lane & 15;
    const int wid  = (int)((blockIdx.x * blockDim.x + threadIdx.x) >> 6);
    const int r    = (wid << 2) + (lane >> 4);
    if ((wid << 2) >= N) return;
    const int  rr    = (r < N) ? r : (N - 1);
    const bool rowok = (r < N);

    const float aw2   = attw[0] * 1.4426950408889634f;   // fold ln2: exp->exp2
    const int   start = rp[rr];
    const int   end   = rowok ? rp[rr + 1] : start;
    const int   cap   = (end > start) ? (end - 1) : start;

    const char* xb = (const char*)Xpb + (t << 3);
    uint2 xw = *(const uint2*)(xb + ((size_t)rr << 7));
    const float xr0 = blo(xw.x), xr1 = bhi(xw.x), xr2 = blo(xw.y), xr3 = bhi(xw.y);

    float acc0 = 0.f, acc1 = 0.f, acc2 = 0.f, acc3 = 0.f, rs = 0.f;

    // prologue: slots A,B = packets 0,1 (8 gathers ~= mean degree);
    // nA,nB = cols for packets 2,3.
    uint2 A0 = GX(CL(start + 0)), A1 = GX(CL(start + 1)),
          A2 = GX(CL(start + 2)), A3 = GX(CL(start + 3));
    uint2 B0 = GX(CL(start + 4)), B1 = GX(CL(start + 5)),
          B2 = GX(CL(start + 6)), B3 = GX(CL(start + 7));
    int nA0 = CL(start +  8), nA1 = CL(start +  9),
        nA2 = CL(start + 10), nA3 = CL(start + 11);
    int nB0 = CL(start + 12), nB1 = CL(start + 13),
        nB2 = CL(start + 14), nB3 = CL(start + 15);

    int e = start;
    for (;;) {
        SUBITER2(A0,A1,A2,A3, nA0,nA1,nA2,nA3)
        SUBITER2(B0,B1,B2,B3, nB0,nB1,nB2,nB3)
    }

    if (rowok) {
        float inv = 1.0f / rs;
        *(float4*)(out + ((size_t)r << 6) + (t << 2)) =
            make_float4(acc0 * inv, acc1 * inv, acc2 * inv, acc3 * inv);
    }
}

// ---------------------------------------------------------------------------
extern "C" void kernel_launch(void* const* d_in, const int* in_sizes, int n_in,
                              void* d_out, int out_size, void* d_ws, size_t ws_size,
                              hipStream_t stream)
{
    const float* X    = (const float*)d_in[0];
    const float* W    = (const float*)d_in[1];
    const float* attw = (const float*)d_in[2];
    const int*   row  = (const int*)d_in[3];
    const int*   col  = (const int*)d_in[4];
    float*       out  = (float*)d_out;

    const int N = in_sizes[0] / 64;
    const int E = in_sizes[3];

    unsigned short* Xpb = (unsigned short*)d_ws;
    int* rp = (int*)((char*)d_ws + (size_t)N * 64 * sizeof(unsigned short));

    const int ntiles = (N + 15) >> 4;
    gemm_rowptr<<<(ntiles + 3) / 4, 256, 0, stream>>>(X, W, row, Xpb, rp, N, E);

    int waves = (N + 3) / 4;
    int gb2   = (waves * 64 + 255) / 256;
    agg<<<gb2, 256, 0, stream>>>(Xpb, rp, col, attw, out, N);
}